// Round 9
// baseline (202.075 us; speedup 1.0000x reference)
//
#include <hip/hip_runtime.h>
#include <hip/hip_bf16.h>

// ---------------- problem constants ----------------
#define BATCH   32768
#define DIM     512
#define H1N     128
#define H2N     256
#define NSUB    20
#define HID     32
#define NCLS    100
#define NHID    640            // NSUB*HID
#define TOTALP  19716          // 512*32 + 32 + 32*100 + 100
#define NPAR    394320         // NSUB*TOTALP
#define WS1P    16384
#define WS1B1   16416          // WS1+BS1
#define WS2END  19616          // WS1+BS1+WS2

// ---------------- ws layout (float units) ----------------
#define OFF_PART 0              // 512*512 partial col sums
#define OFF_H    262144         // 256 f32 hypernet h
#define OFF_W    262400         // 32 f32 softmax(ens_w)
#define OFF_B1   262432         // 640 f32
#define OFF_B2R  263072         // 2000 f32 raw b2
#define OFF_W1B  265072         // bf16 640*512   (163840 f32 slots)
#define OFF_W2B  428912         // bf16 128*640   (40960 f32 slots)
#define OFF_XB   469872         // bf16 32768*512 (8388608 f32 slots)

typedef __attribute__((ext_vector_type(8))) short short8;
typedef __attribute__((ext_vector_type(4))) float f32x4;

static __device__ inline unsigned short f2bf(float f) {
    __hip_bfloat16 h = __float2bfloat16(f);
    return *reinterpret_cast<unsigned short*>(&h);
}

static __device__ __forceinline__ void gload16(const void* g, void* l) {
    __builtin_amdgcn_global_load_lds(
        (const __attribute__((address_space(1))) void*)g,
        (__attribute__((address_space(3))) void*)l, 16, 0, 0);
}

// ---------------- K1: partial column sums + bf16 convert of x ----------------
__global__ __launch_bounds__(256) void k1_colsum(const float* __restrict__ x,
                                                 float* __restrict__ F) {
    __shared__ float sP[DIM];
    int t = threadIdx.x, bid = blockIdx.x;
    int par = t >> 7;            // 0 or 1
    int c4 = (t & 127) * 4;
    const float* xb = x + (size_t)bid * 64 * DIM;
    unsigned short* ob = (unsigned short*)(F + OFF_XB) + (size_t)bid * 64 * DIM;
    float4 acc = make_float4(0.f, 0.f, 0.f, 0.f);
    #pragma unroll 8
    for (int i = 0; i < 32; ++i) {
        int r = 2 * i + par;
        float4 v = *(const float4*)(xb + r * DIM + c4);
        acc.x += v.x; acc.y += v.y; acc.z += v.z; acc.w += v.w;
        ushort4 u;
        u.x = f2bf(v.x); u.y = f2bf(v.y); u.z = f2bf(v.z); u.w = f2bf(v.w);
        *(ushort4*)(ob + r * DIM + c4) = u;
    }
    if (par == 0) *(float4*)(sP + c4) = acc;
    __syncthreads();
    if (par == 1) {
        float4 p = *(const float4*)(sP + c4);
        p.x += acc.x; p.y += acc.y; p.z += acc.z; p.w += acc.w;
        *(float4*)(F + OFF_PART + bid * DIM + c4) = p;
    }
}

// ---------------- K2: hypernet trunk (1 block) ----------
__global__ __launch_bounds__(256) void k2_hyper(
    const float* __restrict__ Wh1, const float* __restrict__ bh1,
    const float* __restrict__ g1,  const float* __restrict__ be1,
    const float* __restrict__ Wh2, const float* __restrict__ bh2,
    const float* __restrict__ g2,  const float* __restrict__ be2,
    const float* __restrict__ ensw, float* __restrict__ F)
{
    __shared__ __align__(16) float sctx[DIM];
    __shared__ __align__(16) float sP2[DIM];
    __shared__ __align__(16) float sh1[H1N];
    __shared__ __align__(16) float sh2[H2N];
    int t = threadIdx.x;

    {
        int c4 = (t & 127) * 4;
        int half = t >> 7;
        float4 a = make_float4(0.f, 0.f, 0.f, 0.f);
        #pragma unroll 8
        for (int b = half * 256; b < half * 256 + 256; ++b) {
            float4 v = *(const float4*)(F + OFF_PART + b * DIM + c4);
            a.x += v.x; a.y += v.y; a.z += v.z; a.w += v.w;
        }
        if (half == 0) *(float4*)(sP2 + c4) = a;
        __syncthreads();
        if (half == 1) {
            float4 o = *(const float4*)(sP2 + c4);
            o.x = (o.x + a.x) * (1.0f / BATCH);
            o.y = (o.y + a.y) * (1.0f / BATCH);
            o.z = (o.z + a.z) * (1.0f / BATCH);
            o.w = (o.w + a.w) * (1.0f / BATCH);
            *(float4*)(sctx + c4) = o;
        }
        __syncthreads();
    }

    if (t < H1N) {
        float v = bh1[t];
        const float4* w = (const float4*)(Wh1 + t * DIM);
        for (int k = 0; k < DIM / 4; ++k) {
            float4 ww = w[k]; float4 c = *(const float4*)(sctx + k * 4);
            v += ww.x * c.x + ww.y * c.y + ww.z * c.z + ww.w * c.w;
        }
        sh1[t] = v;
    }
    __syncthreads();
    {
        float mu = 0.f;
        for (int k = 0; k < H1N; ++k) mu += sh1[k];
        mu *= (1.0f / H1N);
        float var = 0.f;
        for (int k = 0; k < H1N; ++k) { float d = sh1[k] - mu; var += d * d; }
        var *= (1.0f / H1N);
        float inv = rsqrtf(var + 1e-5f);
        __syncthreads();
        if (t < H1N) {
            float v = (sh1[t] - mu) * inv * g1[t] + be1[t];
            sh1[t] = fmaxf(v, 0.f);
        }
        __syncthreads();
    }

    {
        float v = bh2[t];
        const float4* w = (const float4*)(Wh2 + t * H1N);
        for (int k = 0; k < H1N / 4; ++k) {
            float4 ww = w[k]; float4 c = *(const float4*)(sh1 + k * 4);
            v += ww.x * c.x + ww.y * c.y + ww.z * c.z + ww.w * c.w;
        }
        sh2[t] = v;
    }
    __syncthreads();
    {
        float mu = 0.f;
        for (int k = 0; k < H2N; ++k) mu += sh2[k];
        mu *= (1.0f / H2N);
        float var = 0.f;
        for (int k = 0; k < H2N; ++k) { float d = sh2[k] - mu; var += d * d; }
        var *= (1.0f / H2N);
        float inv = rsqrtf(var + 1e-5f);
        float v = (sh2[t] - mu) * inv * g2[t] + be2[t];
        F[OFF_H + t] = fmaxf(v, 0.f);
    }

    if (t == 0) {
        float m = -1e30f;
        for (int s = 0; s < NSUB; ++s) m = fmaxf(m, ensw[s]);
        float sum = 0.f, e[NSUB];
        for (int s = 0; s < NSUB; ++s) { e[s] = __expf(ensw[s] - m); sum += e[s]; }
        for (int s = 0; s < NSUB; ++s) F[OFF_W + s] = e[s] / sum;
    }
}

// ---------------- K3: params GEMV fused with pack/convert --------------------
static __device__ __forceinline__ void k3_pack(float* F, int row, float val) {
    __hip_bfloat16* W1B = (__hip_bfloat16*)(F + OFF_W1B);
    __hip_bfloat16* W2B = (__hip_bfloat16*)(F + OFF_W2B);
    int s = row / TOTALP;
    int r = row - s * TOTALP;
    if (r < WS1P) {
        int hh = r >> 9, k = r & 511;
        W1B[(s * HID + hh) * DIM + k] = __float2bfloat16(val);
    } else if (r < WS1B1) {
        F[OFF_B1 + s * HID + (r - WS1P)] = val;
    } else if (r < WS2END) {
        int q = r - WS1B1; int c = q >> 5, hh = q & 31;
        float ws = F[OFF_W + s];
        W2B[c * NHID + s * HID + hh] = __float2bfloat16(ws * val);
    } else {
        F[OFF_B2R + s * NCLS + (r - WS2END)] = val;
    }
}

__global__ __launch_bounds__(256) void k3_gemv(
    const float* __restrict__ Wh3, const float* __restrict__ bh3, float* __restrict__ F)
{
    int t = threadIdx.x;
    int wid = t >> 6, lane = t & 63;
    int row0 = blockIdx.x * 8 + wid * 2;   // 2 rows per wave
    const float4 h = *(const float4*)(F + OFF_H + lane * 4);
    const float4 w0 = *(const float4*)(Wh3 + (size_t)row0 * 256 + lane * 4);
    const float4 w1 = *(const float4*)(Wh3 + (size_t)(row0 + 1) * 256 + lane * 4);
    float d0 = w0.x * h.x + w0.y * h.y + w0.z * h.z + w0.w * h.w;
    float d1 = w1.x * h.x + w1.y * h.y + w1.z * h.z + w1.w * h.w;
    #pragma unroll
    for (int off = 32; off; off >>= 1) {
        d0 += __shfl_down(d0, off);
        d1 += __shfl_down(d1, off);
    }
    if (lane == 0) {
        k3_pack(F, row0,     d0 + bh3[row0]);
        k3_pack(F, row0 + 1, d1 + bh3[row0 + 1]);
    }
}

// ---------------- K5: fused dual GEMM, 2-phase pipelined (T3) ----------------
// BM=64, 4 waves in 2x2 grid (wave tile 32 rows x 64 cols). 50 uniform phases:
// per chunk n1: ph 0..7 = stage-1 K-steps (BK=64), ph 8..9 = W2 halves.
// Each iteration: STAGE(p+1, buf^1) issued FIRST, then MFMA(p, buf), then one
// __syncthreads() (its vmcnt drain overlaps the MFMA phase). LDS dbuf:
// sA 2x8K + sB 2x16K + sP 16K = 64KB -> 2 blocks/CU.
__global__ __launch_bounds__(256) void gemm_fused(
    const __hip_bfloat16* __restrict__ XB, const __hip_bfloat16* __restrict__ W1B,
    const __hip_bfloat16* __restrict__ W2B, const float* __restrict__ F,
    float* __restrict__ out)
{
    __shared__ __align__(16) unsigned char sA[2][64 * 128];
    __shared__ __align__(16) unsigned char sB[2][128 * 128];
    __shared__ __align__(16) unsigned char sP[64 * 256];
    const int t = threadIdx.x;
    int bid = blockIdx.x;
    const int cpx = gridDim.x >> 3;
    bid = (bid & 7) * cpx + (bid >> 3);
    const int Row0 = bid * 64;
    const int wid = t >> 6, lane = t & 63;
    const int l16 = lane & 15, lq = lane >> 4;
    const int wr = wid >> 1, wc = wid & 1;

    f32x4 acc1[2][4], acc2[2][4];
    #pragma unroll
    for (int fm = 0; fm < 2; ++fm)
        #pragma unroll
        for (int fn = 0; fn < 4; ++fn)
            acc2[fm][fn] = (f32x4){0.f, 0.f, 0.f, 0.f};

    auto stage = [&](int p, int b) {
        int n1 = p / 10, ph = p - n1 * 10;
        if (ph < 8) {
            int kc = ph * 64;
            #pragma unroll
            for (int i = 0; i < 2; ++i) {
                int cidx = wid * 2 + i;
                int ul = cidx * 64 + lane;
                int row = ul >> 3, u = ul & 7;
                gload16(XB + (size_t)(Row0 + row) * 512 + kc + ((u ^ (row & 7)) << 3),
                        &sA[b][cidx * 1024]);
            }
            #pragma unroll
            for (int i = 0; i < 4; ++i) {
                int cidx = wid * 4 + i;
                int ul = cidx * 64 + lane;
                int row = ul >> 3, u = ul & 7;
                gload16(W1B + (size_t)(n1 * 128 + row) * 512 + kc + ((u ^ (row & 7)) << 3),
                        &sB[b][cidx * 1024]);
            }
        } else {
            int h = ph - 8;
            #pragma unroll
            for (int i = 0; i < 4; ++i) {
                int cidx = wid * 4 + i;
                int ul = cidx * 64 + lane;
                int row = ul >> 3, u = ul & 7;
                gload16(W2B + (size_t)row * NHID + n1 * 128 + h * 64 + ((u ^ (row & 7)) << 3),
                        &sB[b][cidx * 1024]);
            }
        }
    };

    auto compute = [&](int p, int b) {
        int n1 = p / 10, ph = p - n1 * 10;
        if (ph < 8) {
            #pragma unroll
            for (int kkl = 0; kkl < 2; ++kkl) {
                int u = kkl * 4 + lq;
                short8 af[2], bfv[4];
                #pragma unroll
                for (int fm = 0; fm < 2; ++fm) {
                    int arow = wr * 32 + fm * 16 + l16;
                    af[fm] = *(const short8*)(&sA[b][arow * 128 + ((u ^ (arow & 7)) << 4)]);
                }
                #pragma unroll
                for (int fn = 0; fn < 4; ++fn) {
                    int brow = wc * 64 + fn * 16 + l16;
                    bfv[fn] = *(const short8*)(&sB[b][brow * 128 + ((u ^ (brow & 7)) << 4)]);
                }
                #pragma unroll
                for (int fm = 0; fm < 2; ++fm)
                    #pragma unroll
                    for (int fn = 0; fn < 4; ++fn)
                        acc1[fm][fn] = __builtin_amdgcn_mfma_f32_16x16x32_bf16(
                            af[fm], bfv[fn], acc1[fm][fn], 0, 0, 0);
            }
        } else {
            int h = ph - 8;
            #pragma unroll
            for (int kkl = 0; kkl < 2; ++kkl) {
                int u = kkl * 4 + lq;
                int punit = (h * 2 + kkl) * 4 + lq;
                short8 af[2], bfv[4];
                #pragma unroll
                for (int fm = 0; fm < 2; ++fm) {
                    int prow = wr * 32 + fm * 16 + l16;
                    af[fm] = *(const short8*)(&sP[prow * 256 + ((punit ^ (prow & 7)) << 4)]);
                }
                #pragma unroll
                for (int fn = 0; fn < 4; ++fn) {
                    int brow = wc * 64 + fn * 16 + l16;
                    bfv[fn] = *(const short8*)(&sB[b][brow * 128 + ((u ^ (brow & 7)) << 4)]);
                }
                #pragma unroll
                for (int fm = 0; fm < 2; ++fm)
                    #pragma unroll
                    for (int fn = 0; fn < 4; ++fn)
                        acc2[fm][fn] = __builtin_amdgcn_mfma_f32_16x16x32_bf16(
                            af[fm], bfv[fn], acc2[fm][fn], 0, 0, 0);
            }
        }
    };

    auto pack = [&](int n1) {
        #pragma unroll
        for (int fm = 0; fm < 2; ++fm) {
            #pragma unroll
            for (int fn = 0; fn < 4; ++fn) {
                int col = wc * 64 + fn * 16 + l16;
                float b1v = F[OFF_B1 + n1 * 128 + col];
                int unit = col >> 3;
                #pragma unroll
                for (int r = 0; r < 4; ++r) {
                    int row = wr * 32 + fm * 16 + lq * 4 + r;
                    float v = fmaxf(acc1[fm][fn][r] + b1v, 0.f);
                    *(unsigned short*)(&sP[row * 256 + ((unit ^ (row & 7)) << 4)
                                       + (col & 7) * 2]) = f2bf(v);
                }
            }
        }
    };

    // prologue
    stage(0, 0);
    __syncthreads();
    int buf = 0;
    for (int p = 0; p < 49; ++p) {
        stage(p + 1, buf ^ 1);
        int ph = p % 10;
        if (ph == 0) {
            #pragma unroll
            for (int fm = 0; fm < 2; ++fm)
                #pragma unroll
                for (int fn = 0; fn < 4; ++fn)
                    acc1[fm][fn] = (f32x4){0.f, 0.f, 0.f, 0.f};
        }
        compute(p, buf);
        if (ph == 7) pack(p / 10);
        __syncthreads();
        buf ^= 1;
    }
    compute(49, buf);
    __syncthreads();

    // be = sum_s w_s * b2raw[s][col] into sBe (alias sA), then epilogue
    float* sBe = (float*)&sA[0][0];
    if (t < 128) {
        float b = 0.f;
        if (t < NCLS) {
            #pragma unroll
            for (int s = 0; s < NSUB; ++s)
                b += F[OFF_W + s] * F[OFF_B2R + s * NCLS + t];
        }
        sBe[t] = b;
    }
    __syncthreads();

    #pragma unroll
    for (int fm = 0; fm < 2; ++fm) {
        #pragma unroll
        for (int fn = 0; fn < 4; ++fn) {
            int gcol = wc * 64 + fn * 16 + l16;
            if (gcol < NCLS) {
                float be = sBe[gcol];
                #pragma unroll
                for (int r = 0; r < 4; ++r) {
                    int grow = Row0 + wr * 32 + fm * 16 + lq * 4 + r;
                    out[(size_t)grow * NCLS + gcol] = acc2[fm][fn][r] + be;
                }
            }
        }
    }
}

// ---------------- launch ----------------
extern "C" void kernel_launch(void* const* d_in, const int* in_sizes, int n_in,
                              void* d_out, int out_size, void* d_ws, size_t ws_size,
                              hipStream_t stream)
{
    const float* x    = (const float*)d_in[0];
    const float* Wh1  = (const float*)d_in[1];
    const float* bh1  = (const float*)d_in[2];
    const float* g1   = (const float*)d_in[3];
    const float* be1  = (const float*)d_in[4];
    const float* Wh2  = (const float*)d_in[5];
    const float* bh2  = (const float*)d_in[6];
    const float* g2   = (const float*)d_in[7];
    const float* be2  = (const float*)d_in[8];
    const float* Wh3  = (const float*)d_in[9];
    const float* bh3  = (const float*)d_in[10];
    const float* ensw = (const float*)d_in[11];
    float* F = (float*)d_ws;
    float* out = (float*)d_out;

    const __hip_bfloat16* XB  = (const __hip_bfloat16*)(F + OFF_XB);
    const __hip_bfloat16* W1B = (const __hip_bfloat16*)(F + OFF_W1B);
    const __hip_bfloat16* W2B = (const __hip_bfloat16*)(F + OFF_W2B);

    k1_colsum<<<512, 256, 0, stream>>>(x, F);
    k2_hyper<<<1, 256, 0, stream>>>(Wh1, bh1, g1, be1, Wh2, bh2, g2, be2, ensw, F);
    k3_gemv<<<NPAR / 8, 256, 0, stream>>>(Wh3, bh3, F);
    // fused: out = relu(XB @ W1B^T + b1) @ W2B^T + be   M=32768, grid 512 x BM=64
    gemm_fused<<<BATCH / 64, 256, 0, stream>>>(XB, W1B, W2B, F, out);
}

// Round 10
// 192.618 us; speedup vs baseline: 1.0491x; 1.0491x over previous
//
#include <hip/hip_runtime.h>
#include <hip/hip_bf16.h>

// ---------------- problem constants ----------------
#define BATCH   32768
#define DIM     512
#define H1N     128
#define H2N     256
#define NSUB    20
#define HID     32
#define NCLS    100
#define NHID    640            // NSUB*HID
#define TOTALP  19716          // 512*32 + 32 + 32*100 + 100
#define NPAR    394320         // NSUB*TOTALP
#define WS1P    16384
#define WS1B1   16416          // WS1+BS1
#define WS2END  19616          // WS1+BS1+WS2

// ---------------- ws layout (float units) ----------------
#define OFF_PART 0              // 512*512 partial col sums
#define OFF_H    262144         // 256 f32 hypernet h
#define OFF_W    262400         // 32 f32 softmax(ens_w)
#define OFF_B1   262432         // 640 f32
#define OFF_B2R  263072         // 2000 f32 raw b2
#define OFF_W1B  265072         // bf16 640*512   (163840 f32 slots)
#define OFF_W2B  428912         // bf16 128*640   (40960 f32 slots)
#define OFF_XB   469872         // bf16 32768*512 (8388608 f32 slots)

typedef __attribute__((ext_vector_type(8))) short short8;
typedef __attribute__((ext_vector_type(4))) float f32x4;

static __device__ inline unsigned short f2bf(float f) {
    __hip_bfloat16 h = __float2bfloat16(f);
    return *reinterpret_cast<unsigned short*>(&h);
}

static __device__ __forceinline__ void gload16(const void* g, void* l) {
    __builtin_amdgcn_global_load_lds(
        (const __attribute__((address_space(1))) void*)g,
        (__attribute__((address_space(3))) void*)l, 16, 0, 0);
}

// ---------------- K1: partial column sums + bf16 convert of x ----------------
__global__ __launch_bounds__(256) void k1_colsum(const float* __restrict__ x,
                                                 float* __restrict__ F) {
    __shared__ float sP[DIM];
    int t = threadIdx.x, bid = blockIdx.x;
    int par = t >> 7;            // 0 or 1
    int c4 = (t & 127) * 4;
    const float* xb = x + (size_t)bid * 64 * DIM;
    unsigned short* ob = (unsigned short*)(F + OFF_XB) + (size_t)bid * 64 * DIM;
    float4 acc = make_float4(0.f, 0.f, 0.f, 0.f);
    #pragma unroll 8
    for (int i = 0; i < 32; ++i) {
        int r = 2 * i + par;
        float4 v = *(const float4*)(xb + r * DIM + c4);
        acc.x += v.x; acc.y += v.y; acc.z += v.z; acc.w += v.w;
        ushort4 u;
        u.x = f2bf(v.x); u.y = f2bf(v.y); u.z = f2bf(v.z); u.w = f2bf(v.w);
        *(ushort4*)(ob + r * DIM + c4) = u;
    }
    if (par == 0) *(float4*)(sP + c4) = acc;
    __syncthreads();
    if (par == 1) {
        float4 p = *(const float4*)(sP + c4);
        p.x += acc.x; p.y += acc.y; p.z += acc.z; p.w += acc.w;
        *(float4*)(F + OFF_PART + bid * DIM + c4) = p;
    }
}

// ---------------- K2: hypernet trunk (1 block) ----------
__global__ __launch_bounds__(256) void k2_hyper(
    const float* __restrict__ Wh1, const float* __restrict__ bh1,
    const float* __restrict__ g1,  const float* __restrict__ be1,
    const float* __restrict__ Wh2, const float* __restrict__ bh2,
    const float* __restrict__ g2,  const float* __restrict__ be2,
    const float* __restrict__ ensw, float* __restrict__ F)
{
    __shared__ __align__(16) float sctx[DIM];
    __shared__ __align__(16) float sP2[DIM];
    __shared__ __align__(16) float sh1[H1N];
    __shared__ __align__(16) float sh2[H2N];
    int t = threadIdx.x;

    {
        int c4 = (t & 127) * 4;
        int half = t >> 7;
        float4 a = make_float4(0.f, 0.f, 0.f, 0.f);
        #pragma unroll 8
        for (int b = half * 256; b < half * 256 + 256; ++b) {
            float4 v = *(const float4*)(F + OFF_PART + b * DIM + c4);
            a.x += v.x; a.y += v.y; a.z += v.z; a.w += v.w;
        }
        if (half == 0) *(float4*)(sP2 + c4) = a;
        __syncthreads();
        if (half == 1) {
            float4 o = *(const float4*)(sP2 + c4);
            o.x = (o.x + a.x) * (1.0f / BATCH);
            o.y = (o.y + a.y) * (1.0f / BATCH);
            o.z = (o.z + a.z) * (1.0f / BATCH);
            o.w = (o.w + a.w) * (1.0f / BATCH);
            *(float4*)(sctx + c4) = o;
        }
        __syncthreads();
    }

    if (t < H1N) {
        float v = bh1[t];
        const float4* w = (const float4*)(Wh1 + t * DIM);
        for (int k = 0; k < DIM / 4; ++k) {
            float4 ww = w[k]; float4 c = *(const float4*)(sctx + k * 4);
            v += ww.x * c.x + ww.y * c.y + ww.z * c.z + ww.w * c.w;
        }
        sh1[t] = v;
    }
    __syncthreads();
    {
        float mu = 0.f;
        for (int k = 0; k < H1N; ++k) mu += sh1[k];
        mu *= (1.0f / H1N);
        float var = 0.f;
        for (int k = 0; k < H1N; ++k) { float d = sh1[k] - mu; var += d * d; }
        var *= (1.0f / H1N);
        float inv = rsqrtf(var + 1e-5f);
        __syncthreads();
        if (t < H1N) {
            float v = (sh1[t] - mu) * inv * g1[t] + be1[t];
            sh1[t] = fmaxf(v, 0.f);
        }
        __syncthreads();
    }

    {
        float v = bh2[t];
        const float4* w = (const float4*)(Wh2 + t * H1N);
        for (int k = 0; k < H1N / 4; ++k) {
            float4 ww = w[k]; float4 c = *(const float4*)(sh1 + k * 4);
            v += ww.x * c.x + ww.y * c.y + ww.z * c.z + ww.w * c.w;
        }
        sh2[t] = v;
    }
    __syncthreads();
    {
        float mu = 0.f;
        for (int k = 0; k < H2N; ++k) mu += sh2[k];
        mu *= (1.0f / H2N);
        float var = 0.f;
        for (int k = 0; k < H2N; ++k) { float d = sh2[k] - mu; var += d * d; }
        var *= (1.0f / H2N);
        float inv = rsqrtf(var + 1e-5f);
        float v = (sh2[t] - mu) * inv * g2[t] + be2[t];
        F[OFF_H + t] = fmaxf(v, 0.f);
    }

    if (t == 0) {
        float m = -1e30f;
        for (int s = 0; s < NSUB; ++s) m = fmaxf(m, ensw[s]);
        float sum = 0.f, e[NSUB];
        for (int s = 0; s < NSUB; ++s) { e[s] = __expf(ensw[s] - m); sum += e[s]; }
        for (int s = 0; s < NSUB; ++s) F[OFF_W + s] = e[s] / sum;
    }
}

// ---------------- K3: params GEMV fused with pack/convert --------------------
static __device__ __forceinline__ void k3_pack(float* F, int row, float val) {
    __hip_bfloat16* W1B = (__hip_bfloat16*)(F + OFF_W1B);
    __hip_bfloat16* W2B = (__hip_bfloat16*)(F + OFF_W2B);
    int s = row / TOTALP;
    int r = row - s * TOTALP;
    if (r < WS1P) {
        int hh = r >> 9, k = r & 511;
        W1B[(s * HID + hh) * DIM + k] = __float2bfloat16(val);
    } else if (r < WS1B1) {
        F[OFF_B1 + s * HID + (r - WS1P)] = val;
    } else if (r < WS2END) {
        int q = r - WS1B1; int c = q >> 5, hh = q & 31;
        float ws = F[OFF_W + s];
        W2B[c * NHID + s * HID + hh] = __float2bfloat16(ws * val);
    } else {
        F[OFF_B2R + s * NCLS + (r - WS2END)] = val;
    }
}

__global__ __launch_bounds__(256) void k3_gemv(
    const float* __restrict__ Wh3, const float* __restrict__ bh3, float* __restrict__ F)
{
    int t = threadIdx.x;
    int wid = t >> 6, lane = t & 63;
    int row0 = blockIdx.x * 8 + wid * 2;   // 2 rows per wave
    const float4 h = *(const float4*)(F + OFF_H + lane * 4);
    const float4 w0 = *(const float4*)(Wh3 + (size_t)row0 * 256 + lane * 4);
    const float4 w1 = *(const float4*)(Wh3 + (size_t)(row0 + 1) * 256 + lane * 4);
    float d0 = w0.x * h.x + w0.y * h.y + w0.z * h.z + w0.w * h.w;
    float d1 = w1.x * h.x + w1.y * h.y + w1.z * h.z + w1.w * h.w;
    #pragma unroll
    for (int off = 32; off; off >>= 1) {
        d0 += __shfl_down(d0, off);
        d1 += __shfl_down(d1, off);
    }
    if (lane == 0) {
        k3_pack(F, row0,     d0 + bh3[row0]);
        k3_pack(F, row0 + 1, d1 + bh3[row0 + 1]);
    }
}

// ---------------- K5: fused dual GEMM, T4 counted-vmcnt pipeline -------------
// BM=64, 4 waves (1x8 tile: wave = 16 rows x 128 cols). 50 phases:
// per chunk n1: ph0..7 = stage-1 BK=64 K-steps, ph8..9 = W2 halves.
// Per phase: STAGE(p+1,buf^1) -> s_waitcnt vmcnt(N_issued) -> s_barrier ->
// compute(p,buf) -> s_barrier. vmcnt never drains to 0 in the loop.
// LDS: sA 2x8K + sB 2x16K + sP 16K = 64 KB -> 2 blocks/CU.
__global__ __launch_bounds__(256) void gemm_fused(
    const __hip_bfloat16* __restrict__ XB, const __hip_bfloat16* __restrict__ W1B,
    const __hip_bfloat16* __restrict__ W2B, const float* __restrict__ F,
    float* __restrict__ out)
{
    __shared__ __align__(16) unsigned char sA[2][64 * 128];
    __shared__ __align__(16) unsigned char sB[2][128 * 128];
    __shared__ __align__(16) unsigned char sP[64 * 256];
    const int t = threadIdx.x;
    int bid = blockIdx.x;
    const int cpx = gridDim.x >> 3;
    bid = (bid & 7) * cpx + (bid >> 3);
    const int Row0 = bid * 64;
    const int wid = t >> 6, lane = t & 63;
    const int l16 = lane & 15, lq = lane >> 4;

    f32x4 acc1[8], acc2[8];
    #pragma unroll
    for (int fn = 0; fn < 8; ++fn) acc2[fn] = (f32x4){0.f, 0.f, 0.f, 0.f};

    // ---- staging helpers (R5-validated layouts) ----
    auto stage1 = [&](int n1, int kc, int b) {
        #pragma unroll
        for (int i = 0; i < 2; ++i) {
            int cidx = wid * 2 + i;
            int ul = cidx * 64 + lane;
            int row = ul >> 3, u = ul & 7;
            gload16(XB + (size_t)(Row0 + row) * 512 + kc + ((u ^ (row & 7)) << 3),
                    &sA[b][cidx * 1024]);
        }
        #pragma unroll
        for (int i = 0; i < 4; ++i) {
            int cidx = wid * 4 + i;
            int ul = cidx * 64 + lane;
            int row = ul >> 3, u = ul & 7;
            gload16(W1B + (size_t)(n1 * 128 + row) * 512 + kc + ((u ^ (row & 7)) << 3),
                    &sB[b][cidx * 1024]);
        }
    };
    auto stageW2 = [&](int n1, int h, int b) {
        #pragma unroll
        for (int i = 0; i < 4; ++i) {
            int cidx = wid * 4 + i;
            int ul = cidx * 64 + lane;
            int row = ul >> 3, u = ul & 7;
            gload16(W2B + (size_t)row * NHID + n1 * 128 + h * 64 + ((u ^ (row & 7)) << 3),
                    &sB[b][cidx * 1024]);
        }
    };
    auto comp1 = [&](int b) {
        #pragma unroll
        for (int kk = 0; kk < 2; ++kk) {
            int u = kk * 4 + lq;
            int arow = wid * 16 + l16;
            short8 af = *(const short8*)(&sA[b][arow * 128 + ((u ^ (arow & 7)) << 4)]);
            short8 bfv[8];
            #pragma unroll
            for (int fn = 0; fn < 8; ++fn) {
                int rw = fn * 16 + l16;
                bfv[fn] = *(const short8*)(&sB[b][rw * 128 + ((u ^ (rw & 7)) << 4)]);
            }
            #pragma unroll
            for (int fn = 0; fn < 8; ++fn)
                acc1[fn] = __builtin_amdgcn_mfma_f32_16x16x32_bf16(
                    af, bfv[fn], acc1[fn], 0, 0, 0);
        }
    };
    auto comp2 = [&](int h, int b) {
        #pragma unroll
        for (int kk = 0; kk < 2; ++kk) {
            int u = kk * 4 + lq;
            int punit = (h * 2 + kk) * 4 + lq;
            int arow = wid * 16 + l16;
            short8 af = *(const short8*)(&sP[arow * 256 + ((punit ^ (arow & 7)) << 4)]);
            short8 bfv[8];
            #pragma unroll
            for (int fn = 0; fn < 8; ++fn) {
                int rw = fn * 16 + l16;
                bfv[fn] = *(const short8*)(&sB[b][rw * 128 + ((u ^ (rw & 7)) << 4)]);
            }
            #pragma unroll
            for (int fn = 0; fn < 8; ++fn)
                acc2[fn] = __builtin_amdgcn_mfma_f32_16x16x32_bf16(
                    af, bfv[fn], acc2[fn], 0, 0, 0);
        }
    };

    // ---- pipeline ----
    int buf = 0;
    stage1(0, 0, 0);
    float b1r[8];

    for (int n1 = 0; n1 < 5; ++n1) {
        #pragma unroll
        for (int st = 0; st < 10; ++st) {
            // issue stage for NEXT phase (skip only at very last phase)
            if (st < 9) {
                if (st + 1 < 8) stage1(n1, (st + 1) * 64, buf ^ 1);
                else stageW2(n1, st + 1 - 8, buf ^ 1);
            } else if (n1 < 4) {
                stage1(n1 + 1, 0, buf ^ 1);
            }
            // counted wait: N = loads just issued (6 stage1, 4 W2), 0 at end
            if (st < 9) {
                if (st + 1 < 8) asm volatile("s_waitcnt vmcnt(6)" ::: "memory");
                else            asm volatile("s_waitcnt vmcnt(4)" ::: "memory");
            } else if (n1 < 4) {
                asm volatile("s_waitcnt vmcnt(6)" ::: "memory");
            } else {
                asm volatile("s_waitcnt vmcnt(0)" ::: "memory");
            }
            __builtin_amdgcn_s_barrier();
            __builtin_amdgcn_sched_barrier(0);

            if (st == 0) {
                #pragma unroll
                for (int fn = 0; fn < 8; ++fn) {
                    acc1[fn] = (f32x4){0.f, 0.f, 0.f, 0.f};
                    b1r[fn] = F[OFF_B1 + n1 * 128 + fn * 16 + l16];
                }
            }
            if (st < 8) comp1(buf);
            else comp2(st - 8, buf);
            if (st == 7) {
                // pack: P = relu(acc1+b1) -> bf16 -> sP (wave-private rows)
                #pragma unroll
                for (int fn = 0; fn < 8; ++fn) {
                    int col = fn * 16 + l16;
                    int unit = col >> 3;
                    #pragma unroll
                    for (int r = 0; r < 4; ++r) {
                        int row = wid * 16 + lq * 4 + r;
                        float v = fmaxf(acc1[fn][r] + b1r[fn], 0.f);
                        *(unsigned short*)(&sP[row * 256 + ((unit ^ (row & 7)) << 4)
                                           + (col & 7) * 2]) = f2bf(v);
                    }
                }
            }
            __builtin_amdgcn_sched_barrier(0);
            __builtin_amdgcn_s_barrier();
            buf ^= 1;
        }
    }

    // be = sum_s w_s * b2raw[s][col] into sBe (alias sA), then epilogue
    float* sBe = (float*)&sA[0][0];
    if (t < 128) {
        float b = 0.f;
        if (t < NCLS) {
            #pragma unroll
            for (int s = 0; s < NSUB; ++s)
                b += F[OFF_W + s] * F[OFF_B2R + s * NCLS + t];
        }
        sBe[t] = b;
    }
    __syncthreads();

    #pragma unroll
    for (int fn = 0; fn < 8; ++fn) {
        int gcol = fn * 16 + l16;
        if (gcol < NCLS) {
            float be = sBe[gcol];
            #pragma unroll
            for (int r = 0; r < 4; ++r) {
                int grow = Row0 + wid * 16 + lq * 4 + r;
                out[(size_t)grow * NCLS + gcol] = acc2[fn][r] + be;
            }
        }
    }
}

// ---------------- launch ----------------
extern "C" void kernel_launch(void* const* d_in, const int* in_sizes, int n_in,
                              void* d_out, int out_size, void* d_ws, size_t ws_size,
                              hipStream_t stream)
{
    const float* x    = (const float*)d_in[0];
    const float* Wh1  = (const float*)d_in[1];
    const float* bh1  = (const float*)d_in[2];
    const float* g1   = (const float*)d_in[3];
    const float* be1  = (const float*)d_in[4];
    const float* Wh2  = (const float*)d_in[5];
    const float* bh2  = (const float*)d_in[6];
    const float* g2   = (const float*)d_in[7];
    const float* be2  = (const float*)d_in[8];
    const float* Wh3  = (const float*)d_in[9];
    const float* bh3  = (const float*)d_in[10];
    const float* ensw = (const float*)d_in[11];
    float* F = (float*)d_ws;
    float* out = (float*)d_out;

    const __hip_bfloat16* XB  = (const __hip_bfloat16*)(F + OFF_XB);
    const __hip_bfloat16* W1B = (const __hip_bfloat16*)(F + OFF_W1B);
    const __hip_bfloat16* W2B = (const __hip_bfloat16*)(F + OFF_W2B);

    k1_colsum<<<512, 256, 0, stream>>>(x, F);
    k2_hyper<<<1, 256, 0, stream>>>(Wh1, bh1, g1, be1, Wh2, bh2, g2, be2, ensw, F);
    k3_gemv<<<NPAR / 8, 256, 0, stream>>>(Wh3, bh3, F);
    // fused: out = relu(XB @ W1B^T + b1) @ W2B^T + be   M=32768, grid 512 x BM=64
    gemm_fused<<<BATCH / 64, 256, 0, stream>>>(XB, W1B, W2B, F, out);
}

// Round 11
// 182.911 us; speedup vs baseline: 1.1048x; 1.0531x over previous
//
#include <hip/hip_runtime.h>
#include <hip/hip_bf16.h>

// ---------------- problem constants ----------------
#define BATCH   32768
#define DIM     512
#define H1N     128
#define H2N     256
#define NSUB    20
#define HID     32
#define NCLS    100
#define NHID    640            // NSUB*HID
#define TOTALP  19716          // 512*32 + 32 + 32*100 + 100
#define NPAR    394320         // NSUB*TOTALP
#define WS1P    16384
#define WS1B1   16416          // WS1+BS1
#define WS2END  19616          // WS1+BS1+WS2

// ---------------- ws layout (float units) ----------------
#define OFF_PART 0              // 512*512 partial col sums
#define OFF_H    262144         // 256 f32 hypernet h
#define OFF_W    262400         // 32 f32 softmax(ens_w)
#define OFF_B1   262432         // 640 f32
#define OFF_B2R  263072         // 2000 f32 raw b2
#define OFF_W1B  265072         // bf16 640*512   (163840 f32 slots)
#define OFF_W2B  428912         // bf16 128*640   (40960 f32 slots)

typedef __attribute__((ext_vector_type(8))) short short8;
typedef __attribute__((ext_vector_type(4))) float f32x4;

static __device__ inline unsigned short f2bf(float f) {
    __hip_bfloat16 h = __float2bfloat16(f);
    return *reinterpret_cast<unsigned short*>(&h);
}

static __device__ __forceinline__ void gload16(const void* g, void* l) {
    __builtin_amdgcn_global_load_lds(
        (const __attribute__((address_space(1))) void*)g,
        (__attribute__((address_space(3))) void*)l, 16, 0, 0);
}

// ---------------- K1: partial column sums of x (pure, no convert) -----------
__global__ __launch_bounds__(256) void k1_colsum(const float* __restrict__ x,
                                                 float* __restrict__ F) {
    __shared__ float sP[DIM];
    int t = threadIdx.x, bid = blockIdx.x;
    int par = t >> 7;            // 0 or 1
    int c4 = (t & 127) * 4;
    const float* xb = x + (size_t)bid * 64 * DIM;
    float4 acc = make_float4(0.f, 0.f, 0.f, 0.f);
    #pragma unroll 8
    for (int i = 0; i < 32; ++i) {
        int r = 2 * i + par;
        float4 v = *(const float4*)(xb + r * DIM + c4);
        acc.x += v.x; acc.y += v.y; acc.z += v.z; acc.w += v.w;
    }
    if (par == 0) *(float4*)(sP + c4) = acc;
    __syncthreads();
    if (par == 1) {
        float4 p = *(const float4*)(sP + c4);
        p.x += acc.x; p.y += acc.y; p.z += acc.z; p.w += acc.w;
        *(float4*)(F + OFF_PART + bid * DIM + c4) = p;
    }
}

// ---------------- K2: hypernet trunk (1 block) ----------
__global__ __launch_bounds__(256) void k2_hyper(
    const float* __restrict__ Wh1, const float* __restrict__ bh1,
    const float* __restrict__ g1,  const float* __restrict__ be1,
    const float* __restrict__ Wh2, const float* __restrict__ bh2,
    const float* __restrict__ g2,  const float* __restrict__ be2,
    const float* __restrict__ ensw, float* __restrict__ F)
{
    __shared__ __align__(16) float sctx[DIM];
    __shared__ __align__(16) float sP2[DIM];
    __shared__ __align__(16) float sh1[H1N];
    __shared__ __align__(16) float sh2[H2N];
    int t = threadIdx.x;

    {
        int c4 = (t & 127) * 4;
        int half = t >> 7;
        float4 a = make_float4(0.f, 0.f, 0.f, 0.f);
        #pragma unroll 8
        for (int b = half * 256; b < half * 256 + 256; ++b) {
            float4 v = *(const float4*)(F + OFF_PART + b * DIM + c4);
            a.x += v.x; a.y += v.y; a.z += v.z; a.w += v.w;
        }
        if (half == 0) *(float4*)(sP2 + c4) = a;
        __syncthreads();
        if (half == 1) {
            float4 o = *(const float4*)(sP2 + c4);
            o.x = (o.x + a.x) * (1.0f / BATCH);
            o.y = (o.y + a.y) * (1.0f / BATCH);
            o.z = (o.z + a.z) * (1.0f / BATCH);
            o.w = (o.w + a.w) * (1.0f / BATCH);
            *(float4*)(sctx + c4) = o;
        }
        __syncthreads();
    }

    if (t < H1N) {
        float v = bh1[t];
        const float4* w = (const float4*)(Wh1 + t * DIM);
        for (int k = 0; k < DIM / 4; ++k) {
            float4 ww = w[k]; float4 c = *(const float4*)(sctx + k * 4);
            v += ww.x * c.x + ww.y * c.y + ww.z * c.z + ww.w * c.w;
        }
        sh1[t] = v;
    }
    __syncthreads();
    {
        float mu = 0.f;
        for (int k = 0; k < H1N; ++k) mu += sh1[k];
        mu *= (1.0f / H1N);
        float var = 0.f;
        for (int k = 0; k < H1N; ++k) { float d = sh1[k] - mu; var += d * d; }
        var *= (1.0f / H1N);
        float inv = rsqrtf(var + 1e-5f);
        __syncthreads();
        if (t < H1N) {
            float v = (sh1[t] - mu) * inv * g1[t] + be1[t];
            sh1[t] = fmaxf(v, 0.f);
        }
        __syncthreads();
    }

    {
        float v = bh2[t];
        const float4* w = (const float4*)(Wh2 + t * H1N);
        for (int k = 0; k < H1N / 4; ++k) {
            float4 ww = w[k]; float4 c = *(const float4*)(sh1 + k * 4);
            v += ww.x * c.x + ww.y * c.y + ww.z * c.z + ww.w * c.w;
        }
        sh2[t] = v;
    }
    __syncthreads();
    {
        float mu = 0.f;
        for (int k = 0; k < H2N; ++k) mu += sh2[k];
        mu *= (1.0f / H2N);
        float var = 0.f;
        for (int k = 0; k < H2N; ++k) { float d = sh2[k] - mu; var += d * d; }
        var *= (1.0f / H2N);
        float inv = rsqrtf(var + 1e-5f);
        float v = (sh2[t] - mu) * inv * g2[t] + be2[t];
        F[OFF_H + t] = fmaxf(v, 0.f);
    }

    if (t == 0) {
        float m = -1e30f;
        for (int s = 0; s < NSUB; ++s) m = fmaxf(m, ensw[s]);
        float sum = 0.f, e[NSUB];
        for (int s = 0; s < NSUB; ++s) { e[s] = __expf(ensw[s] - m); sum += e[s]; }
        for (int s = 0; s < NSUB; ++s) F[OFF_W + s] = e[s] / sum;
    }
}

// ---------------- K3: params GEMV fused with pack/convert --------------------
static __device__ __forceinline__ void k3_pack(float* F, int row, float val) {
    __hip_bfloat16* W1B = (__hip_bfloat16*)(F + OFF_W1B);
    __hip_bfloat16* W2B = (__hip_bfloat16*)(F + OFF_W2B);
    int s = row / TOTALP;
    int r = row - s * TOTALP;
    if (r < WS1P) {
        int hh = r >> 9, k = r & 511;
        W1B[(s * HID + hh) * DIM + k] = __float2bfloat16(val);
    } else if (r < WS1B1) {
        F[OFF_B1 + s * HID + (r - WS1P)] = val;
    } else if (r < WS2END) {
        int q = r - WS1B1; int c = q >> 5, hh = q & 31;
        float ws = F[OFF_W + s];
        W2B[c * NHID + s * HID + hh] = __float2bfloat16(ws * val);
    } else {
        F[OFF_B2R + s * NCLS + (r - WS2END)] = val;
    }
}

__global__ __launch_bounds__(256) void k3_gemv(
    const float* __restrict__ Wh3, const float* __restrict__ bh3, float* __restrict__ F)
{
    int t = threadIdx.x;
    int wid = t >> 6, lane = t & 63;
    int row0 = blockIdx.x * 8 + wid * 2;   // 2 rows per wave
    const float4 h = *(const float4*)(F + OFF_H + lane * 4);
    const float4 w0 = *(const float4*)(Wh3 + (size_t)row0 * 256 + lane * 4);
    const float4 w1 = *(const float4*)(Wh3 + (size_t)(row0 + 1) * 256 + lane * 4);
    float d0 = w0.x * h.x + w0.y * h.y + w0.z * h.z + w0.w * h.w;
    float d1 = w1.x * h.x + w1.y * h.y + w1.z * h.z + w1.w * h.w;
    #pragma unroll
    for (int off = 32; off; off >>= 1) {
        d0 += __shfl_down(d0, off);
        d1 += __shfl_down(d1, off);
    }
    if (lane == 0) {
        k3_pack(F, row0,     d0 + bh3[row0]);
        k3_pack(F, row0 + 1, d1 + bh3[row0 + 1]);
    }
}

// ---------------- K5: fused dual GEMM, A-in-registers + T4 pipeline ----------
// BM=64, 4 waves (1x8 tile). A fragments for all K=512 live in afr[16] (64
// VGPR), loaded ONCE from x (f32) and converted in-kernel — no sA, no XB pass.
// 50 phases: per chunk n1: ph0..7 = stage-1 BK=64 K-steps (stage W1B only),
// ph8..9 = W2 halves. Per phase: STAGE(next, buf^1) [4 loads] ->
// s_waitcnt vmcnt(4) -> s_barrier -> compute -> s_barrier.
// LDS: sB 2x16K + sP 16K = 48 KB.
__global__ __launch_bounds__(256) void gemm_fused(
    const float* __restrict__ x, const __hip_bfloat16* __restrict__ W1B,
    const __hip_bfloat16* __restrict__ W2B, const float* __restrict__ F,
    float* __restrict__ out)
{
    __shared__ __align__(16) unsigned char sB[2][128 * 128];
    __shared__ __align__(16) unsigned char sP[64 * 256];
    const int t = threadIdx.x;
    int bid = blockIdx.x;
    const int cpx = gridDim.x >> 3;
    bid = (bid & 7) * cpx + (bid >> 3);
    const int Row0 = bid * 64;
    const int wid = t >> 6, lane = t & 63;
    const int l16 = lane & 15, lq = lane >> 4;

    f32x4 acc1[8], acc2[8];
    #pragma unroll
    for (int fn = 0; fn < 8; ++fn) acc2[fn] = (f32x4){0.f, 0.f, 0.f, 0.f};

    auto stageW1 = [&](int n1, int kc, int b) {
        #pragma unroll
        for (int i = 0; i < 4; ++i) {
            int cidx = wid * 4 + i;
            int ul = cidx * 64 + lane;
            int row = ul >> 3, u = ul & 7;
            gload16(W1B + (size_t)(n1 * 128 + row) * 512 + kc + ((u ^ (row & 7)) << 3),
                    &sB[b][cidx * 1024]);
        }
    };
    auto stageW2 = [&](int n1, int h, int b) {
        #pragma unroll
        for (int i = 0; i < 4; ++i) {
            int cidx = wid * 4 + i;
            int ul = cidx * 64 + lane;
            int row = ul >> 3, u = ul & 7;
            gload16(W2B + (size_t)row * NHID + n1 * 128 + h * 64 + ((u ^ (row & 7)) << 3),
                    &sB[b][cidx * 1024]);
        }
    };

    // ---- prologue: issue first W1B stage, then load+convert A under it ----
    stageW1(0, 0, 0);

    short8 afr[16];                    // A fragments, whole K; 64 VGPR
    {
        const float* xrow = x + (size_t)(Row0 + wid * 16 + l16) * 512;
        #pragma unroll
        for (int i = 0; i < 16; ++i) { // i = st*2+kk ; k0 = st*64+kk*32+lq*8
            int k0 = (i >> 1) * 64 + (i & 1) * 32 + lq * 8;
            float4 a = *(const float4*)(xrow + k0);
            float4 b = *(const float4*)(xrow + k0 + 4);
            unsigned int p[4];
            p[0] = (unsigned)f2bf(a.x) | ((unsigned)f2bf(a.y) << 16);
            p[1] = (unsigned)f2bf(a.z) | ((unsigned)f2bf(a.w) << 16);
            p[2] = (unsigned)f2bf(b.x) | ((unsigned)f2bf(b.y) << 16);
            p[3] = (unsigned)f2bf(b.z) | ((unsigned)f2bf(b.w) << 16);
            afr[i] = *(short8*)p;
        }
    }
    asm volatile("s_waitcnt vmcnt(0)" ::: "memory");
    __builtin_amdgcn_s_barrier();

    auto comp1 = [&](int st, int b) {
        #pragma unroll
        for (int kk = 0; kk < 2; ++kk) {
            int u = kk * 4 + lq;
            short8 af = afr[st * 2 + kk];
            short8 bfv[8];
            #pragma unroll
            for (int fn = 0; fn < 8; ++fn) {
                int rw = fn * 16 + l16;
                bfv[fn] = *(const short8*)(&sB[b][rw * 128 + ((u ^ (rw & 7)) << 4)]);
            }
            #pragma unroll
            for (int fn = 0; fn < 8; ++fn)
                acc1[fn] = __builtin_amdgcn_mfma_f32_16x16x32_bf16(
                    af, bfv[fn], acc1[fn], 0, 0, 0);
        }
    };
    auto comp2 = [&](int h, int b) {
        #pragma unroll
        for (int kk = 0; kk < 2; ++kk) {
            int u = kk * 4 + lq;
            int punit = (h * 2 + kk) * 4 + lq;
            int arow = wid * 16 + l16;
            short8 af = *(const short8*)(&sP[arow * 256 + ((punit ^ (arow & 7)) << 4)]);
            short8 bfv[8];
            #pragma unroll
            for (int fn = 0; fn < 8; ++fn) {
                int rw = fn * 16 + l16;
                bfv[fn] = *(const short8*)(&sB[b][rw * 128 + ((u ^ (rw & 7)) << 4)]);
            }
            #pragma unroll
            for (int fn = 0; fn < 8; ++fn)
                acc2[fn] = __builtin_amdgcn_mfma_f32_16x16x32_bf16(
                    af, bfv[fn], acc2[fn], 0, 0, 0);
        }
    };

    // ---- pipeline: 50 phases ----
    int buf = 0;
    float b1r[8];
    for (int n1 = 0; n1 < 5; ++n1) {
        #pragma unroll
        for (int st = 0; st < 10; ++st) {
            if (st < 9) {
                if (st + 1 < 8) stageW1(n1, (st + 1) * 64, buf ^ 1);
                else stageW2(n1, st + 1 - 8, buf ^ 1);
            } else if (n1 < 4) {
                stageW1(n1 + 1, 0, buf ^ 1);
            }
            if (st == 9 && n1 == 4)
                asm volatile("s_waitcnt vmcnt(0)" ::: "memory");
            else
                asm volatile("s_waitcnt vmcnt(4)" ::: "memory");
            __builtin_amdgcn_s_barrier();
            __builtin_amdgcn_sched_barrier(0);

            if (st == 0) {
                #pragma unroll
                for (int fn = 0; fn < 8; ++fn) {
                    acc1[fn] = (f32x4){0.f, 0.f, 0.f, 0.f};
                    b1r[fn] = F[OFF_B1 + n1 * 128 + fn * 16 + l16];
                }
            }
            if (st < 8) comp1(st, buf);
            else comp2(st - 8, buf);
            if (st == 7) {
                // pack: P = relu(acc1+b1) -> bf16 -> sP (wave-private rows)
                #pragma unroll
                for (int fn = 0; fn < 8; ++fn) {
                    int col = fn * 16 + l16;
                    int unit = col >> 3;
                    #pragma unroll
                    for (int r = 0; r < 4; ++r) {
                        int row = wid * 16 + lq * 4 + r;
                        float v = fmaxf(acc1[fn][r] + b1r[fn], 0.f);
                        *(unsigned short*)(&sP[row * 256 + ((unit ^ (row & 7)) << 4)
                                           + (col & 7) * 2]) = f2bf(v);
                    }
                }
            }
            __builtin_amdgcn_sched_barrier(0);
            __builtin_amdgcn_s_barrier();
            buf ^= 1;
        }
    }

    // be = sum_s w_s * b2raw[s][col] into sBe (alias sP, free now)
    float* sBe = (float*)sP;
    if (t < 128) {
        float b = 0.f;
        if (t < NCLS) {
            #pragma unroll
            for (int s = 0; s < NSUB; ++s)
                b += F[OFF_W + s] * F[OFF_B2R + s * NCLS + t];
        }
        sBe[t] = b;
    }
    __syncthreads();

    #pragma unroll
    for (int fn = 0; fn < 8; ++fn) {
        int gcol = fn * 16 + l16;
        if (gcol < NCLS) {
            float be = sBe[gcol];
            #pragma unroll
            for (int r = 0; r < 4; ++r) {
                int grow = Row0 + wid * 16 + lq * 4 + r;
                out[(size_t)grow * NCLS + gcol] = acc2[fn][r] + be;
            }
        }
    }
}

// ---------------- launch ----------------
extern "C" void kernel_launch(void* const* d_in, const int* in_sizes, int n_in,
                              void* d_out, int out_size, void* d_ws, size_t ws_size,
                              hipStream_t stream)
{
    const float* x    = (const float*)d_in[0];
    const float* Wh1  = (const float*)d_in[1];
    const float* bh1  = (const float*)d_in[2];
    const float* g1   = (const float*)d_in[3];
    const float* be1  = (const float*)d_in[4];
    const float* Wh2  = (const float*)d_in[5];
    const float* bh2  = (const float*)d_in[6];
    const float* g2   = (const float*)d_in[7];
    const float* be2  = (const float*)d_in[8];
    const float* Wh3  = (const float*)d_in[9];
    const float* bh3  = (const float*)d_in[10];
    const float* ensw = (const float*)d_in[11];
    float* F = (float*)d_ws;
    float* out = (float*)d_out;

    const __hip_bfloat16* W1B = (const __hip_bfloat16*)(F + OFF_W1B);
    const __hip_bfloat16* W2B = (const __hip_bfloat16*)(F + OFF_W2B);

    k1_colsum<<<512, 256, 0, stream>>>(x, F);
    k2_hyper<<<1, 256, 0, stream>>>(Wh1, bh1, g1, be1, Wh2, bh2, g2, be2, ensw, F);
    k3_gemv<<<NPAR / 8, 256, 0, stream>>>(Wh3, bh3, F);
    // fused: out = relu(x@W1^T+b1) @ W2^T + be   M=32768, grid 512 x BM=64
    gemm_fused<<<BATCH / 64, 256, 0, stream>>>(x, W1B, W2B, F, out);
}